// Round 1
// 392.736 us; speedup vs baseline: 1.1630x; 1.1630x over previous
//
#include <hip/hip_runtime.h>
#include <hip/hip_fp16.h>

// UniversalGRU: 2-layer GRU (B=2048, T=512, D=1, H=64) + FC(64->1).
// R8 = R7 with the inter-lane gate redistribution ELIMINATED by row
// remapping: batch row b lives at MFMA A-row m = 4*(b>>1)+(b&1), so each
// lane's accumulator regs [0],[1] (D rows 4q,4q+1) ARE its two real rows
// (b = 2q, 2q+1). This deletes all pack/shfl(ds_bpermute)/unpack/cndmask
// per gate group (L0: -3 DS ops -15 VALU, L1: -4 DS -20 VALU per
// wave-step), removes the lgkm stall from the gate critical path, and
// removes the f16 round-trip the old redistribution introduced.
// Also R8: sigmoid/tanh pre-scaled into the weights (r,z rows *= log2e,
// n rows *= 2*log2e, biases likewise) so activations use raw v_exp_f32
// (exp2) with a free input-negate instead of a per-op log2e multiply.
// Structure unchanged: layer-skewed (waves 0-3 = L0 step t, waves 4-7 =
// L1 step t-1), 1 barrier/t, 256 blocks x 512 threads.

#define T_LEN 512
#define ROWS  8
#define XPAD  513
#define LOG2E 1.44269504088896f

typedef float          f32x4 __attribute__((ext_vector_type(4)));
typedef __bf16         bf16x8 __attribute__((ext_vector_type(8)));
typedef unsigned short us8   __attribute__((ext_vector_type(8)));
typedef unsigned short ushort_t;

__device__ __forceinline__ float bf2f(ushort_t b){
    unsigned int u = ((unsigned int)b) << 16;
    return __uint_as_float(u);
}
__device__ __forceinline__ ushort_t f2bf(float f){
    unsigned int u = __float_as_uint(f);
    u = (u + 0x7FFFu + ((u >> 16) & 1u)) >> 16;   // RNE
    return (ushort_t)u;
}
__device__ __forceinline__ float ld_any(const void* p, int i, bool f32){
    return f32 ? ((const float*)p)[i] : bf2f(((const ushort_t*)p)[i]);
}
__device__ __forceinline__ float exp2_fast(float x){
#if __has_builtin(__builtin_amdgcn_exp2f)
    return __builtin_amdgcn_exp2f(x);          // v_exp_f32 (2^x)
#else
    return __expf(0.6931471805599453f * x);    // fallback, same value
#endif
}
// sigma(x) with pre-scaled argument t = log2e * x
__device__ __forceinline__ float sigm2(float t){
    return __fdividef(1.0f, 1.0f + exp2_fast(-t));
}
// tanh(y) with pre-scaled argument t = 2*log2e * y
__device__ __forceinline__ float tanh2(float t){
    return fmaf(-2.0f, __fdividef(1.0f, exp2_fast(t) + 1.0f), 1.0f);
}
__device__ __forceinline__ f32x4 mfma16(bf16x8 a, bf16x8 b, f32x4 c){
    return __builtin_amdgcn_mfma_f32_16x16x32_bf16(a, b, c, 0, 0, 0);
}
// Build a B-fragment (8 contiguous k's of W[n][k]) from either dtype,
// with the activation pre-scale folded in before the bf16 rounding.
__device__ __forceinline__ bf16x8 mk_frag(const void* W, int n, int kb, bool f32, float sc){
    us8 tmp;
    #pragma unroll
    for (int j = 0; j < 8; ++j){
        float v = f32 ? ((const float*)W)[n * 64 + kb + j]
                      : bf2f(((const ushort_t*)W)[n * 64 + kb + j]);
        tmp[j] = f2bf(v * sc);
    }
    return __builtin_bit_cast(bf16x8, tmp);
}

__global__ __launch_bounds__(512, 2) void gru_fused(
    const void* __restrict__ xv,
    const void* __restrict__ Wih0, const void* __restrict__ Whh0,
    const void* __restrict__ bih0, const void* __restrict__ bhh0,
    const void* __restrict__ Wih1, const void* __restrict__ Whh1,
    const void* __restrict__ bih1, const void* __restrict__ bhh1,
    const void* __restrict__ Wfc,  const void* __restrict__ bfc,
    void* __restrict__ outv)
{
    __shared__ float    xbuf[ROWS * XPAD];       // staged x, padded stride
    __shared__ ushort_t hbufA[2][16 * 72];       // layer-0 h, A-layout bf16, dbuf
    __shared__ ushort_t hbufB[2][16 * 72];       // layer-1 h
    __shared__ float    outb[ROWS][68];          // final h2 for FC

    const int tid  = threadIdx.x;
    const int wv   = tid >> 6;                   // 0..7
    const bool isL1 = (wv >= 4);
    const int w    = wv & 3;                     // n-tile group within role
    const int c    = tid & 15;                   // MFMA col-within-tile
    const int q    = (tid >> 4) & 3;             // quad -> D rows 4q..4q+3
    const int ih   = w * 16 + c;                 // h-col this lane's gates own
    const int r0   = 2 * q;                      // lane's first REAL batch row
    const int m0   = 4 * q;                      // its A-row (b=2q+j <-> m=4q+j)
    const long row0 = (long)blockIdx.x * ROWS;

    // dtype detection (uniform): fp32 misread as bf16 -> mantissa-noise
    // exponents in even ushort slots; true bf16 never exceeds exp 150.
    bool f32 = false;
    {
        const ushort_t* xs = (const ushort_t*)xv;
        for (int j = 0; j < 64; ++j){
            int e = (xs[2 * j] >> 7) & 0xFF;
            if (e > 150) f32 = true;
        }
    }

    // zero h double-buffers (h0 = 0; pad rows m=4q+2,4q+3 stay 0 forever)
    {
        ushort_t* pa = &hbufA[0][0];
        ushort_t* pb = &hbufB[0][0];
        for (int k = tid; k < 2 * 16 * 72; k += 512){ pa[k] = 0; pb[k] = 0; }
    }
    // stage x: wave wv loads batch row wv (8 rows x 512), coalesced
    {
        const int r = wv;
        const int g = tid & 63;
        if (f32){
            const f32x4* src = (const f32x4*)((const float*)xv + (row0 + r) * T_LEN);
            #pragma unroll
            for (int it = 0; it < 2; ++it){
                f32x4 v = src[g + 64 * it];
                #pragma unroll
                for (int j = 0; j < 4; ++j)
                    xbuf[r * XPAD + (g + 64 * it) * 4 + j] = v[j];
            }
        } else {
            const us8* src = (const us8*)((const ushort_t*)xv + (row0 + r) * T_LEN);
            us8 v = src[g];
            #pragma unroll
            for (int j = 0; j < 8; ++j)
                xbuf[r * XPAD + g * 8 + j] = bf2f(v[j]);
        }
    }

    // Role-specific weights (pre-scaled: r,z by log2e; n by 2*log2e).
    // B[k][n]=W[n][k]; lane: n = 64*g + ih, k = 32*f + 8*q + j.
    bf16x8 wA[3][2], wB[3][2];                   // L0: wA=Whh0. L1: wA=Wih1, wB=Whh1.
    float sxr = 0.f, sxz = 0.f, sxn = 0.f;       // L0 scalar x-weights
    float br, bz, bnx, bnh;
    const float gsc0 = LOG2E, gsc2 = 2.0f * LOG2E;
    if (!isL1){
        #pragma unroll
        for (int g = 0; g < 3; ++g){
            const int n = g * 64 + ih;
            const float sc = (g == 2) ? gsc2 : gsc0;
            #pragma unroll
            for (int f = 0; f < 2; ++f)
                wA[g][f] = mk_frag(Whh0, n, f * 32 + q * 8, f32, sc);
        }
        sxr = ld_any(Wih0, ih, f32) * gsc0;
        sxz = ld_any(Wih0, 64 + ih, f32) * gsc0;
        sxn = ld_any(Wih0, 128 + ih, f32) * gsc2;
        br  = (ld_any(bih0, ih, f32)      + ld_any(bhh0, ih, f32))      * gsc0;
        bz  = (ld_any(bih0, 64 + ih, f32) + ld_any(bhh0, 64 + ih, f32)) * gsc0;
        bnx = ld_any(bih0, 128 + ih, f32) * gsc2;
        bnh = ld_any(bhh0, 128 + ih, f32) * gsc2;
    } else {
        #pragma unroll
        for (int g = 0; g < 3; ++g){
            const int n = g * 64 + ih;
            const float sc = (g == 2) ? gsc2 : gsc0;
            #pragma unroll
            for (int f = 0; f < 2; ++f){
                wA[g][f] = mk_frag(Wih1, n, f * 32 + q * 8, f32, sc);
                wB[g][f] = mk_frag(Whh1, n, f * 32 + q * 8, f32, sc);
            }
        }
        br  = (ld_any(bih1, ih, f32)      + ld_any(bhh1, ih, f32))      * gsc0;
        bz  = (ld_any(bih1, 64 + ih, f32) + ld_any(bhh1, 64 + ih, f32)) * gsc0;
        bnx = ld_any(bih1, 128 + ih, f32) * gsc2;
        bnh = ld_any(bhh1, 128 + ih, f32) * gsc2;
    }

    float h2[2] = {0.f, 0.f};          // fp32-carried h for rows r0, r0+1
    const int aoff = c * 72 + q * 8;   // A-frag base: A[m=c][k=8q(+32f)]

    __syncthreads();

    for (int t = 0; t < T_LEN; ++t){
        const int p = t & 1;
        if (!isL1){
            // ---- layer 0, step t: hA(t) = GRU0(x(t), hA(t-1))
            us8 a0u = *(const us8*)&hbufA[p][aoff];
            us8 a1u = *(const us8*)&hbufA[p][aoff + 32];
            bf16x8 a0 = __builtin_bit_cast(bf16x8, a0u);
            bf16x8 a1 = __builtin_bit_cast(bf16x8, a1u);
            f32x4 aR = {br, br, br, br};
            f32x4 aZ = {bz, bz, bz, bz};
            f32x4 aN = {bnh, bnh, bnh, bnh};
            aR = mfma16(a0, wA[0][0], aR); aR = mfma16(a1, wA[0][1], aR);
            aZ = mfma16(a0, wA[1][0], aZ); aZ = mfma16(a1, wA[1][1], aZ);
            aN = mfma16(a0, wA[2][0], aN); aN = mfma16(a1, wA[2][1], aN);
            // regs [0],[1] are this lane's own real rows -- no shuffle.
            float xm[2] = { xbuf[r0 * XPAD + t], xbuf[(r0 + 1) * XPAD + t] };
            #pragma unroll
            for (int j = 0; j < 2; ++j){
                float rg = sigm2(fmaf(xm[j], sxr, aR[j]));
                float zg = sigm2(fmaf(xm[j], sxz, aZ[j]));
                float ng = tanh2(fmaf(xm[j], sxn, bnx) + rg * aN[j]);
                h2[j] = ng + zg * (h2[j] - ng);
                hbufA[p ^ 1][(m0 + j) * 72 + ih] = f2bf(h2[j]);
            }
        } else if (t > 0){
            // ---- layer 1, step t-1: hB(t-1) = GRU1(hA(t-1), hB(t-2))
            us8 a0u = *(const us8*)&hbufA[p][aoff];        // hA(t-1)
            us8 a1u = *(const us8*)&hbufA[p][aoff + 32];
            us8 b0u = *(const us8*)&hbufB[p][aoff];        // hB(t-2)
            us8 b1u = *(const us8*)&hbufB[p][aoff + 32];
            bf16x8 a0 = __builtin_bit_cast(bf16x8, a0u);
            bf16x8 a1 = __builtin_bit_cast(bf16x8, a1u);
            bf16x8 b0 = __builtin_bit_cast(bf16x8, b0u);
            bf16x8 b1 = __builtin_bit_cast(bf16x8, b1u);
            f32x4 aR  = {br, br, br, br};
            f32x4 aZ  = {bz, bz, bz, bz};
            f32x4 aXn = {bnx, bnx, bnx, bnx};
            f32x4 aHn = {bnh, bnh, bnh, bnh};
            aR  = mfma16(a0, wA[0][0], aR);  aR  = mfma16(a1, wA[0][1], aR);
            aR  = mfma16(b0, wB[0][0], aR);  aR  = mfma16(b1, wB[0][1], aR);
            aZ  = mfma16(a0, wA[1][0], aZ);  aZ  = mfma16(a1, wA[1][1], aZ);
            aZ  = mfma16(b0, wB[1][0], aZ);  aZ  = mfma16(b1, wB[1][1], aZ);
            aXn = mfma16(a0, wA[2][0], aXn); aXn = mfma16(a1, wA[2][1], aXn);
            aHn = mfma16(b0, wB[2][0], aHn); aHn = mfma16(b1, wB[2][1], aHn);
            #pragma unroll
            for (int j = 0; j < 2; ++j){
                float rg = sigm2(aR[j]);
                float zg = sigm2(aZ[j]);
                float ng = tanh2(aXn[j] + rg * aHn[j]);
                h2[j] = ng + zg * (h2[j] - ng);
                hbufB[p ^ 1][(m0 + j) * 72 + ih] = f2bf(h2[j]);
            }
        }
        __syncthreads();
    }

    // Epilogue: L1 waves compute the final step hB(511) from hA(511), hB(510)
    // (both sit in buffer 0 after 512 iterations).
    if (isL1){
        us8 a0u = *(const us8*)&hbufA[0][aoff];
        us8 a1u = *(const us8*)&hbufA[0][aoff + 32];
        us8 b0u = *(const us8*)&hbufB[0][aoff];
        us8 b1u = *(const us8*)&hbufB[0][aoff + 32];
        bf16x8 a0 = __builtin_bit_cast(bf16x8, a0u);
        bf16x8 a1 = __builtin_bit_cast(bf16x8, a1u);
        bf16x8 b0 = __builtin_bit_cast(bf16x8, b0u);
        bf16x8 b1 = __builtin_bit_cast(bf16x8, b1u);
        f32x4 aR  = {br, br, br, br};
        f32x4 aZ  = {bz, bz, bz, bz};
        f32x4 aXn = {bnx, bnx, bnx, bnx};
        f32x4 aHn = {bnh, bnh, bnh, bnh};
        aR  = mfma16(a0, wA[0][0], aR);  aR  = mfma16(a1, wA[0][1], aR);
        aR  = mfma16(b0, wB[0][0], aR);  aR  = mfma16(b1, wB[0][1], aR);
        aZ  = mfma16(a0, wA[1][0], aZ);  aZ  = mfma16(a1, wA[1][1], aZ);
        aZ  = mfma16(b0, wB[1][0], aZ);  aZ  = mfma16(b1, wB[1][1], aZ);
        aXn = mfma16(a0, wA[2][0], aXn); aXn = mfma16(a1, wA[2][1], aXn);
        aHn = mfma16(b0, wB[2][0], aHn); aHn = mfma16(b1, wB[2][1], aHn);
        #pragma unroll
        for (int j = 0; j < 2; ++j){
            float rg = sigm2(aR[j]);
            float zg = sigm2(aZ[j]);
            float ng = tanh2(aXn[j] + rg * aHn[j]);
            float hf = ng + zg * (h2[j] - ng);
            outb[r0 + j][ih] = hf;
        }
    }
    __syncthreads();

    // FC: out[row] = sum_i Wfc[i]*h2[row][i] + bfc
    if (tid < ROWS){
        float s = ld_any(bfc, 0, f32);
        for (int i2 = 0; i2 < 64; ++i2) s = fmaf(ld_any(Wfc, i2, f32), outb[tid][i2], s);
        if (f32) ((float*)outv)[row0 + tid] = s;
        else     ((ushort_t*)outv)[row0 + tid] = f2bf(s);
    }
}

extern "C" void kernel_launch(void* const* d_in, const int* in_sizes, int n_in,
                              void* d_out, int out_size, void* d_ws, size_t ws_size,
                              hipStream_t stream)
{
    (void)in_sizes; (void)n_in; (void)d_ws; (void)ws_size;
    const int B = out_size;            // O = 1 -> out_size == batch
    const int nblk = B / ROWS;         // 2048/8 = 256 blocks
    gru_fused<<<nblk, 512, 0, stream>>>(
        d_in[0],
        d_in[1], d_in[2], d_in[3], d_in[4],
        d_in[5], d_in[6], d_in[7], d_in[8],
        d_in[9], d_in[10],
        d_out);
}